// Round 2
// baseline (68.458 us; speedup 1.0000x reference)
//
#include <hip/hip_runtime.h>
#include <math.h>

#define BATCH 8
#define NPTS 4096
#define BN (BATCH * NPTS)      /* 32768 */
#define RBLK 8                 /* i-points per thread */
#define TPB 256                /* threads per block   */
#define ICOV (RBLK * TPB)      /* 2048 i per block    */
#define NIC (NPTS / ICOV)      /* 2 i-chunks          */

// Workspace (floats):
//   [0, 2*BN)        scaled coords (x*s, y*s) interleaved
//   [2*BN, 3*BN)     scaled weights (w * norm)
//   [3*BN, ...)      partials [njc][B][N]

__global__ __launch_bounds__(TPB)
void kde_prep(const float* __restrict__ w, const float* __restrict__ c,
              const float* __restrict__ sigma,
              float* __restrict__ sc, float* __restrict__ sw) {
    int idx = blockIdx.x * TPB + threadIdx.x;
    float sg     = sigma[0];
    float inv2s2 = 1.0f / (2.0f * sg * sg);
    float s      = sqrtf(inv2s2 * 1.4426950408889634f); // fold log2(e)
    float norm   = inv2s2 * 0.3183098861837907f;        // 1/(2*pi*sg^2)
    float2 cc = ((const float2*)c)[idx];
    ((float2*)sc)[idx] = make_float2(cc.x * s, cc.y * s);
    sw[idx] = w[idx] * norm;
}

template<int JCHUNK>
__global__ __launch_bounds__(TPB)
void kde_main(const float* __restrict__ sc, const float* __restrict__ sw,
              float* __restrict__ part) {
    __shared__ __align__(16) float xs[JCHUNK];
    __shared__ __align__(16) float ys[JCHUNK];
    __shared__ __align__(16) float wl[JCHUNK];

    int b  = blockIdx.x;
    int ic = blockIdx.y;
    int jc = blockIdx.z;
    int j0 = jc * JCHUNK;
    const float2* scb = (const float2*)sc + b * NPTS;

    for (int t = threadIdx.x; t < JCHUNK; t += TPB) {
        float2 cj = scb[j0 + t];
        xs[t] = cj.x;
        ys[t] = cj.y;
        wl[t] = sw[b * NPTS + j0 + t];
    }
    __syncthreads();

    int ibase = ic * ICOV + threadIdx.x;    // stride-TPB i layout: coalesced
    float cx[RBLK], cy[RBLK], acc[RBLK];
#pragma unroll
    for (int r = 0; r < RBLK; ++r) {
        float2 ci = scb[ibase + r * TPB];
        cx[r] = ci.x; cy[r] = ci.y; acc[r] = 0.0f;
    }

#pragma unroll 1
    for (int g = 0; g < JCHUNK / 4; ++g) {
        float4 X = *(const float4*)&xs[g * 4];   // ds_read_b128 (broadcast)
        float4 Y = *(const float4*)&ys[g * 4];
        float4 W = *(const float4*)&wl[g * 4];
        const float* Xp = (const float*)&X;
        const float* Yp = (const float*)&Y;
        const float* Wp = (const float*)&W;
#pragma unroll
        for (int k = 0; k < 4; ++k) {
            float xj = Xp[k], yj = Yp[k], wj = Wp[k];
#pragma unroll
            for (int r = 0; r < RBLK; ++r) {
                float dx = cx[r] - xj;
                float dy = cy[r] - yj;
                float e  = fmaf(dx, dx, dy * dy);
                acc[r] = fmaf(exp2f(-e), wj, acc[r]);  // v_exp_f32(neg) + v_fmac
            }
        }
    }

#pragma unroll
    for (int r = 0; r < RBLK; ++r)
        part[(jc * BATCH + b) * NPTS + ibase + r * TPB] = acc[r];
}

__global__ __launch_bounds__(TPB)
void kde_reduce(const float* __restrict__ part, float* __restrict__ out, int njc) {
    int idx = blockIdx.x * TPB + threadIdx.x;   // 0 .. BN-1
    float s = 0.0f;
    for (int jc = 0; jc < njc; ++jc)
        s += part[jc * BN + idx];
    out[idx] = s;
}

extern "C" void kernel_launch(void* const* d_in, const int* in_sizes, int n_in,
                              void* d_out, int out_size, void* d_ws, size_t ws_size,
                              hipStream_t stream) {
    const float* w     = (const float*)d_in[0];
    const float* c     = (const float*)d_in[1];
    const float* sigma = (const float*)d_in[2];
    float* out = (float*)d_out;

    float* sc   = (float*)d_ws;
    float* sw   = sc + 2 * BN;
    float* part = sw + BN;

    kde_prep<<<BN / TPB, TPB, 0, stream>>>(w, c, sigma, sc, sw);

    // pick the largest j-split that fits the workspace: need (3 + njc)*BN*4 B
    size_t avail = (ws_size > (size_t)3 * BN * 4) ? (ws_size - (size_t)3 * BN * 4) : 0;
    int njc_max = (int)(avail / ((size_t)BN * 4));

    int njc;
    if (njc_max >= 64) {
        njc = 64;
        kde_main<64><<<dim3(BATCH, NIC, njc), TPB, 0, stream>>>(sc, sw, part);
    } else if (njc_max >= 32) {
        njc = 32;
        kde_main<128><<<dim3(BATCH, NIC, njc), TPB, 0, stream>>>(sc, sw, part);
    } else if (njc_max >= 16) {
        njc = 16;
        kde_main<256><<<dim3(BATCH, NIC, njc), TPB, 0, stream>>>(sc, sw, part);
    } else {
        njc = 8;
        kde_main<512><<<dim3(BATCH, NIC, njc), TPB, 0, stream>>>(sc, sw, part);
    }

    kde_reduce<<<BN / TPB, TPB, 0, stream>>>(part, out, njc);
}

// Round 3
// 30.856 us; speedup vs baseline: 2.2186x; 2.2186x over previous
//
#include <hip/hip_runtime.h>
#include <math.h>

#define BATCH 8
#define NPTS 4096
#define BN (BATCH * NPTS)      /* 32768 */
#define TPB 256
#define RBLK 8                 /* i-points per thread  */
#define ICOV (RBLK * TPB)      /* 2048 i per block     */
#define NIC (NPTS / ICOV)      /* 2 i-chunks           */
#define ESHIFT 96.0f           /* exponent bias against f32 overflow */
#define LOG2E 1.4426950408889634f

static __device__ __forceinline__ float fast_exp2(float x) {
#if __has_builtin(__builtin_amdgcn_exp2f)
    return __builtin_amdgcn_exp2f(x);   // raw v_exp_f32, no OCML wrapper
#else
    return exp2f(x);
#endif
}

// term(i,j) = w_j * 2^(-kap*d2) ; kap = log2e/(2 sg^2)
// exponent = xi'*jx + yi'*jy + Cj  with
//   jx = 2*kap*xj', jy = 2*kap*yj', Cj = -kap*|xj'|^2 + log2(wj) - ESHIFT
// (primes = centered coords). Per-i factor 2^(ESHIFT - kap*|xi'|^2)*norm in reduce.
template<int JCHUNK>
__global__ __launch_bounds__(TPB)
void kde_main(const float* __restrict__ w, const float* __restrict__ c,
              const float* __restrict__ sigma, float* __restrict__ part) {
    __shared__ __align__(16) float jxs[JCHUNK];
    __shared__ __align__(16) float jys[JCHUNK];
    __shared__ __align__(16) float jcs[JCHUNK];

    int b   = blockIdx.x;
    int ic  = blockIdx.y;
    int jcb = blockIdx.z;
    int j0  = jcb * JCHUNK;

    float sg  = sigma[0];
    float kap = LOG2E / (2.0f * sg * sg);
    const float2* cb = (const float2*)c + b * NPTS;

    for (int t = threadIdx.x; t < JCHUNK; t += TPB) {
        float2 cj = cb[j0 + t];
        float xj = cj.x - 0.5f, yj = cj.y - 0.5f;
        float aj = fmaf(xj, xj, yj * yj);
        jxs[t] = 2.0f * kap * xj;
        jys[t] = 2.0f * kap * yj;
        jcs[t] = fmaf(-kap, aj, log2f(w[b * NPTS + j0 + t]) - ESHIFT);
    }
    __syncthreads();

    int ibase = ic * ICOV + threadIdx.x;   // stride-TPB: coalesced
    float cx[RBLK], cy[RBLK], acc[RBLK];
#pragma unroll
    for (int r = 0; r < RBLK; ++r) {
        float2 ci = cb[ibase + r * TPB];
        cx[r] = ci.x - 0.5f;
        cy[r] = ci.y - 0.5f;
        acc[r] = 0.0f;
    }

#pragma unroll 1
    for (int g = 0; g < JCHUNK / 4; ++g) {
        float4 X = *(const float4*)&jxs[g * 4];   // ds_read_b128 broadcast
        float4 Y = *(const float4*)&jys[g * 4];
        float4 C = *(const float4*)&jcs[g * 4];
        const float* Xp = (const float*)&X;
        const float* Yp = (const float*)&Y;
        const float* Cp = (const float*)&C;
#pragma unroll
        for (int k = 0; k < 4; ++k) {
#pragma unroll
            for (int r = 0; r < RBLK; ++r) {
                float t0  = fmaf(cy[r], Yp[k], Cp[k]);
                float arg = fmaf(cx[r], Xp[k], t0);
                acc[r] += fast_exp2(arg);          // v_fma,v_fma,v_exp,v_add
            }
        }
    }

#pragma unroll
    for (int r = 0; r < RBLK; ++r)
        part[(jcb * BATCH + b) * NPTS + ibase + r * TPB] = acc[r];
}

__global__ __launch_bounds__(TPB)
void kde_reduce(const float* __restrict__ part, const float* __restrict__ c,
                const float* __restrict__ sigma, float* __restrict__ out, int njc) {
    int idx = blockIdx.x * TPB + threadIdx.x;    // 0 .. BN-1
    float sg   = sigma[0];
    float kap  = LOG2E / (2.0f * sg * sg);
    float norm = 0.15915494309189535f / (sg * sg);  // 1/(2*pi*sg^2)
    float2 ci = ((const float2*)c)[idx];
    float xi = ci.x - 0.5f, yi = ci.y - 0.5f;
    float ai = fmaf(xi, xi, yi * yi);
    float fi = norm * exp2f(fmaf(-kap, ai, ESHIFT));
    float s = 0.0f;
#pragma unroll 8
    for (int q = 0; q < njc; ++q)
        s += part[q * BN + idx];
    out[idx] = fi * s;
}

extern "C" void kernel_launch(void* const* d_in, const int* in_sizes, int n_in,
                              void* d_out, int out_size, void* d_ws, size_t ws_size,
                              hipStream_t stream) {
    const float* w     = (const float*)d_in[0];
    const float* c     = (const float*)d_in[1];
    const float* sigma = (const float*)d_in[2];
    float* out  = (float*)d_out;
    float* part = (float*)d_ws;   // [njc][B][N] partials only

    int njc_max = (int)(ws_size / ((size_t)BN * 4));
    int njc;
    if (njc_max >= 64) {
        njc = 64;
        kde_main<64><<<dim3(BATCH, NIC, 64), TPB, 0, stream>>>(w, c, sigma, part);
    } else if (njc_max >= 32) {
        njc = 32;
        kde_main<128><<<dim3(BATCH, NIC, 32), TPB, 0, stream>>>(w, c, sigma, part);
    } else if (njc_max >= 16) {
        njc = 16;
        kde_main<256><<<dim3(BATCH, NIC, 16), TPB, 0, stream>>>(w, c, sigma, part);
    } else {
        njc = 8;
        kde_main<512><<<dim3(BATCH, NIC, 8), TPB, 0, stream>>>(w, c, sigma, part);
    }

    kde_reduce<<<BN / TPB, TPB, 0, stream>>>(part, c, sigma, out, njc);
}

// Round 4
// 27.255 us; speedup vs baseline: 2.5117x; 1.1321x over previous
//
#include <hip/hip_runtime.h>
#include <math.h>

#define BATCH 8
#define NPTS 4096
#define BN (BATCH * NPTS)      /* 32768 */
#define TPB 256
#define RBLK 8                 /* i-points per thread  */
#define ICOV (RBLK * TPB)      /* 2048 i per block     */
#define NIC (NPTS / ICOV)      /* 2 i-chunks           */
#define ESHIFT 96.0f           /* exponent bias against f32 overflow */
#define LOG2E 1.4426950408889634f

typedef float v2f __attribute__((ext_vector_type(2)));

static __device__ __forceinline__ float fast_exp2(float x) {
#if __has_builtin(__builtin_amdgcn_exp2f)
    return __builtin_amdgcn_exp2f(x);   // raw v_exp_f32
#else
    return exp2f(x);
#endif
}

// term(i,j) = w_j * 2^(-kap*d2), kap = log2e/(2 sg^2)
// exponent  = xi'*jx + yi'*jy + Cj
//   jx = 2*kap*xj', jy = 2*kap*yj', Cj = -kap*|xj'|^2 + log2(wj) - ESHIFT
// per-i factor 2^(ESHIFT - kap*|xi'|^2) * norm applied in reduce.
template<int JCHUNK>
__global__ __launch_bounds__(TPB)
void kde_main(const float* __restrict__ w, const float* __restrict__ c,
              const float* __restrict__ sigma, float* __restrict__ part) {
    __shared__ __align__(16) float jxs[JCHUNK];
    __shared__ __align__(16) float jys[JCHUNK];
    __shared__ __align__(16) float jcs[JCHUNK];

    int b   = blockIdx.x;
    int ic  = blockIdx.y;
    int jcb = blockIdx.z;
    int j0  = jcb * JCHUNK;

    float sg  = sigma[0];
    float kap = LOG2E / (2.0f * sg * sg);
    const float2* cb = (const float2*)c + b * NPTS;

    for (int t = threadIdx.x; t < JCHUNK; t += TPB) {
        float2 cj = cb[j0 + t];
        float xj = cj.x - 0.5f, yj = cj.y - 0.5f;
        float aj = fmaf(xj, xj, yj * yj);
        jxs[t] = 2.0f * kap * xj;
        jys[t] = 2.0f * kap * yj;
        jcs[t] = fmaf(-kap, aj, log2f(w[b * NPTS + j0 + t]) - ESHIFT);
    }
    __syncthreads();

    int ibase = ic * ICOV + threadIdx.x;   // stride-TPB: coalesced
    v2f cx2[RBLK], cy2[RBLK], acc2[RBLK];
#pragma unroll
    for (int r = 0; r < RBLK; ++r) {
        float2 ci = cb[ibase + r * TPB];
        float xi = ci.x - 0.5f, yi = ci.y - 0.5f;
        cx2[r] = (v2f){xi, xi};
        cy2[r] = (v2f){yi, yi};
        acc2[r] = (v2f){0.0f, 0.0f};
    }

#pragma unroll 1
    for (int g = 0; g < JCHUNK / 4; ++g) {
        float4 X = *(const float4*)&jxs[g * 4];   // ds_read_b128 broadcast
        float4 Y = *(const float4*)&jys[g * 4];
        float4 C = *(const float4*)&jcs[g * 4];
        const v2f* Xh = (const v2f*)&X;           // two j-pairs per float4
        const v2f* Yh = (const v2f*)&Y;
        const v2f* Ch = (const v2f*)&C;
#pragma unroll
        for (int h = 0; h < 2; ++h) {
            v2f xj = Xh[h], yj = Yh[h], cj = Ch[h];
#pragma unroll
            for (int r = 0; r < RBLK; ++r) {
                v2f t = cy2[r] * yj + cj;          // v_pk_fma_f32
                v2f a = cx2[r] * xj + t;           // v_pk_fma_f32
                v2f e = (v2f){fast_exp2(a.x), fast_exp2(a.y)};
                acc2[r] += e;                      // v_pk_add_f32
            }
        }
    }

#pragma unroll
    for (int r = 0; r < RBLK; ++r)
        part[(jcb * BATCH + b) * NPTS + ibase + r * TPB] = acc2[r].x + acc2[r].y;
}

__global__ __launch_bounds__(TPB)
void kde_reduce(const float* __restrict__ part, const float* __restrict__ c,
                const float* __restrict__ sigma, float* __restrict__ out, int njc) {
    int idx = blockIdx.x * TPB + threadIdx.x;    // 0 .. BN-1
    float sg   = sigma[0];
    float kap  = LOG2E / (2.0f * sg * sg);
    float norm = 0.15915494309189535f / (sg * sg);  // 1/(2*pi*sg^2)
    float2 ci = ((const float2*)c)[idx];
    float xi = ci.x - 0.5f, yi = ci.y - 0.5f;
    float ai = fmaf(xi, xi, yi * yi);
    float fi = norm * exp2f(fmaf(-kap, ai, ESHIFT));
    float s0 = 0.0f, s1 = 0.0f;
#pragma unroll 8
    for (int q = 0; q < njc; q += 2) {
        s0 += part[q * BN + idx];
        s1 += part[(q + 1) * BN + idx];
    }
    out[idx] = fi * (s0 + s1);
}

extern "C" void kernel_launch(void* const* d_in, const int* in_sizes, int n_in,
                              void* d_out, int out_size, void* d_ws, size_t ws_size,
                              hipStream_t stream) {
    const float* w     = (const float*)d_in[0];
    const float* c     = (const float*)d_in[1];
    const float* sigma = (const float*)d_in[2];
    float* out  = (float*)d_out;
    float* part = (float*)d_ws;   // [njc][B][N]

    int njc_max = (int)(ws_size / ((size_t)BN * 4));
    int njc;
    if (njc_max >= 64) {
        njc = 64;
        kde_main<64><<<dim3(BATCH, NIC, 64), TPB, 0, stream>>>(w, c, sigma, part);
    } else if (njc_max >= 32) {
        njc = 32;
        kde_main<128><<<dim3(BATCH, NIC, 32), TPB, 0, stream>>>(w, c, sigma, part);
    } else if (njc_max >= 16) {
        njc = 16;
        kde_main<256><<<dim3(BATCH, NIC, 16), TPB, 0, stream>>>(w, c, sigma, part);
    } else {
        njc = 8;
        kde_main<512><<<dim3(BATCH, NIC, 8), TPB, 0, stream>>>(w, c, sigma, part);
    }

    kde_reduce<<<BN / TPB, TPB, 0, stream>>>(part, c, sigma, out, njc);
}